// Round 1
// 9840.611 us; speedup vs baseline: 1.2247x; 1.2247x over previous
//
#include <hip/hip_runtime.h>
#include <hip/hip_bf16.h>
#include <cstdint>

// ---------------------------------------------------------------------------
// Seq2Seq (B=64, S=128, T=64, V=10000, E=128, H=256).
// ALL float tensors are FLOAT32 (per reference, jnp.float32) — inputs read as
// const float*, d_out written as float*. MFMA compute in bf16 via one-time
// per-launch weight conversion into a module-global bf16 pool.
// Encoder: 2-layer biLSTM. NEW: batch-split recurrence — grid = 8 blocks
// (dir x 4 batch-groups of 16), h/c block-local, ZERO inter-block sync.
// Whh streamed from L2 with 5/8 of each wave's slice register-stationary.
// Decoder: 63 steps of attention + LSTMCell + V-projection (unchanged).
// ---------------------------------------------------------------------------

typedef __hip_bfloat16 bf16;
typedef __attribute__((ext_vector_type(8))) short short8;   // 8 bf16 = 4 VGPRs
typedef __attribute__((ext_vector_type(4))) float f32x4;

// ---- bf16 weight pool offsets (elements) ----------------------------------
#define OFF_E1F_WIH 0L
#define OFF_E1B_WIH 131072L
#define OFF_E2F_WIH 262144L
#define OFF_E2B_WIH 786432L
#define OFF_E1F_WHH 1310720L
#define OFF_E1B_WHH 1572864L
#define OFF_E2F_WHH 1835008L
#define OFF_E2B_WHH 2097152L
#define OFF_DWIH    2359296L
#define OFF_WFC     3014656L
#define OFF_WA      10694656L
#define WBF_TOTAL   10891264L

// ---- module-scope scratch (allocated at .so load) -------------------------
__device__ __align__(16) bf16     g_WBF[WBF_TOTAL];     // 21.8 MB bf16 weights
__device__ __align__(16) float    g_X1F[8192 * 1024];   // 32 MB gate preacts fwd
__device__ __align__(16) float    g_X1B[8192 * 1024];   // 32 MB gate preacts bwd
__device__ __align__(16) bf16     g_EMB[8192 * 128];    // 2 MB embedded src
__device__ __align__(16) bf16     g_OUT1[8192 * 512];   // 8 MB layer-1 output
__device__ __align__(16) bf16     g_ENC[8192 * 512];    // 8 MB encoder output
__device__ __align__(16) float    g_EWA[8192 * 256];    // 8 MB enc@Wa[:,H:]^T
__device__ __align__(16) float    g_HID[64 * 256];      // decoder hidden (f32)
__device__ __align__(16) bf16     g_XIN[64 * 640];      // [emb|ctx]
__device__ __align__(16) bf16     g_HC[64 * 768];       // [h|ctx]

__device__ __forceinline__ float b2f(bf16 x) { return __bfloat162float(x); }
__device__ __forceinline__ float fexp2(float x) { return __builtin_amdgcn_exp2f(x); }
__device__ __forceinline__ float frcp(float x)  { return __builtin_amdgcn_rcpf(x); }
__device__ __forceinline__ float clampf(float x, float L) {
  return fminf(fmaxf(x, -L), L);       // NaN -> -L
}
__device__ __forceinline__ float sigf(float x) {
  x = clampf(x, 30.f);
  return frcp(1.f + fexp2(-1.44269504f * x));
}
__device__ __forceinline__ float tanh_f(float x) {
  x = clampf(x, 15.f);
  float e = fexp2(2.885390082f * x);          // e^(2x)
  return (e - 1.f) * frcp(e + 1.f);
}
__device__ __forceinline__ f32x4 mfma16(short8 a, short8 b, f32x4 c) {
  return __builtin_amdgcn_mfma_f32_16x16x32_bf16(a, b, c, 0, 0, 0);
}

// ---------------------------------------------------------------------------
// f32 -> bf16 weight conversion into pool (n multiple of 4)
__global__ __launch_bounds__(256) void cvt_w(const float* __restrict__ src,
                                             long off, int n) {
  int i = (blockIdx.x * 256 + threadIdx.x) * 4;
  if (i >= n) return;
  float4 v = *(const float4*)(src + i);
  bf16* d = g_WBF + off + i;
  d[0] = __float2bfloat16(v.x);
  d[1] = __float2bfloat16(v.y);
  d[2] = __float2bfloat16(v.z);
  d[3] = __float2bfloat16(v.w);
}

// emb[b*S+s][e] = enc_emb[src[b][s]][e]  (f32 table -> bf16)
__global__ __launch_bounds__(256) void embed_k(const int* __restrict__ src,
                                               const float* __restrict__ tab) {
  int i4 = (blockIdx.x * 256 + threadIdx.x) * 4;      // 8192*128 elems
  int row = i4 >> 7, e = i4 & 127;
  int tok = src[row];
  if (tok < 0 || tok >= 10000) tok = 0;               // defensive
  float4 v = *(const float4*)&tab[(size_t)tok * 128 + e];
  bf16* d = &g_EMB[(size_t)row * 128 + e];
  d[0] = __float2bfloat16(v.x);
  d[1] = __float2bfloat16(v.y);
  d[2] = __float2bfloat16(v.z);
  d[3] = __float2bfloat16(v.w);
}

// ---------------------------------------------------------------------------
// C[M,N] = A[M,K] @ W[N,K]^T + bias(f32).  Writes f32 (Cf), clamped.
// grid = (M/64, ceil(N/64)); block 256 = 4 waves; wave w: rows [bx*64+16w,+16).
__device__ __forceinline__ void gemm_core(const bf16* __restrict__ A, int lda,
                                          const bf16* __restrict__ W, int ldw, int wcol,
                                          const float* __restrict__ bias,
                                          float* __restrict__ Cf,
                                          long ldc, int N, int K, float clampL) {
  const int wave = threadIdx.x >> 6, lane = threadIdx.x & 63;
  const int l15 = lane & 15, quad = lane >> 4;
  const int m0 = blockIdx.x * 64 + wave * 16;
  const int n0 = blockIdx.y * 64;

  f32x4 acc[4];
#pragma unroll
  for (int j = 0; j < 4; ++j) acc[j] = (f32x4){0.f, 0.f, 0.f, 0.f};

  const bf16* Arow = A + (size_t)(m0 + l15) * lda + quad * 8;
  for (int k = 0; k < K; k += 32) {
    short8 a = *(const short8*)(Arow + k);
#pragma unroll
    for (int j = 0; j < 4; ++j) {
      int n = n0 + 16 * j + l15;
      short8 bfr = (short8){0, 0, 0, 0, 0, 0, 0, 0};
      if (n < N) bfr = *(const short8*)(W + (size_t)n * ldw + wcol + k + quad * 8);
      acc[j] = mfma16(a, bfr, acc[j]);
    }
  }
#pragma unroll
  for (int j = 0; j < 4; ++j) {
    int n = n0 + 16 * j + l15;
    if (n >= N) continue;
    float bv = bias ? bias[n] : 0.f;
#pragma unroll
    for (int r = 0; r < 4; ++r) {
      int m = m0 + quad * 4 + r;
      Cf[(size_t)m * ldc + n] = clampf(acc[j][r] + bv, clampL);
    }
  }
}

// layer-1 input GEMM: g_EMB[8192,128] @ W[1024,128]^T -> g_X1F/g_X1B (f32)
__global__ __launch_bounds__(256) void gemm_x1(long offW, const float* __restrict__ bias,
                                               int bwd) {
  gemm_core(g_EMB, 128, g_WBF + offW, 128, 0, bias, bwd ? g_X1B : g_X1F,
            1024, 1024, 128, 64.f);
}
// layer-2 input GEMM: g_OUT1[8192,512] @ W[1024,512]^T -> g_X1F/g_X1B (reuse)
__global__ __launch_bounds__(256) void gemm_x2(long offW, const float* __restrict__ bias,
                                               int bwd) {
  gemm_core(g_OUT1, 512, g_WBF + offW, 512, 0, bias, bwd ? g_X1B : g_X1F,
            1024, 1024, 512, 64.f);
}
// attention precompute: g_ENC[8192,512] @ Wa[:,256:768]^T -> g_EWA (f32)
__global__ __launch_bounds__(256) void gemm_ewa() {
  gemm_core(g_ENC, 512, g_WBF + OFF_WA, 768, 256, nullptr, g_EWA, 256, 256, 512, 64.f);
}
// prediction: g_HC[64,768] @ Wfc[10000,768]^T + bfc -> outp+step*10000 (f32)
__global__ __launch_bounds__(256) void gemm_pred(const float* __restrict__ bfc,
                                                 float* __restrict__ outp, int step) {
  gemm_core(g_HC, 768, g_WBF + OFF_WFC, 768, 0, bfc, outp + (size_t)step * 10000,
            640000, 10000, 768, 512.f);
}

// ---------------------------------------------------------------------------
// Batch-split persistent biLSTM layer. grid = 8: dir d = bx&1, batch-group
// bg = bx>>1 (batches [16bg, 16bg+16)). Block = 256 thr = 4 waves; wave w
// computes gate w's full 256 columns (Whh rows [256w, 256w+256)).
// h (bf16) and c (registers) are block-local -> NO inter-block sync at all.
// Whh: kt 0..4 (K-cols 0..159) register-stationary (80 short8 = 320 VGPR),
// kt 5..7 streamed from L2 each step (192 KB/block/step).
// __launch_bounds__(256,1): 1 block/CU, full 512-VGPR budget per wave.
// Gate math path (fragment layout, k-order, clamps) identical to previous
// u-split kernel -> bitwise-identical h/c trajectory.
__global__ __launch_bounds__(256, 1) void lstm_batch(long offWhf, long offWhb,
                                                     int layer) {
  const int bx = blockIdx.x;
  const int d = bx & 1, bg = bx >> 1;
  const int b0 = bg * 16;
  const float* __restrict__ X  = d ? g_X1B : g_X1F;
  const bf16*  __restrict__ Wh = g_WBF + (d ? offWhb : offWhf);
  bf16* __restrict__ out = layer ? g_ENC : g_OUT1;     // [64][128][512]

  __shared__ __align__(16) bf16 hlds[16 * 264];        // h tile, pitch 264
  __shared__ float gst[16 * 1028];                     // gates staging (f32)

  const int tid = threadIdx.x;
  const int wave = tid >> 6, lane = tid & 63, l15 = lane & 15, quad = lane >> 4;
  const int n0 = wave * 256;                           // wave = gate

  // ---- stationary B frags: kt 0..4, nt 0..15 (320 VGPRs) ----
  short8 bs[5][16];
#pragma unroll
  for (int kt = 0; kt < 5; ++kt)
#pragma unroll
    for (int nt = 0; nt < 16; ++nt)
      bs[kt][nt] = *(const short8*)(Wh + (size_t)(n0 + 16 * nt + l15) * 256 +
                                    kt * 32 + quad * 8);

  for (int i = tid; i < 16 * 264; i += 256) hlds[i] = __float2bfloat16(0.f);
  float creg[16];
#pragma unroll
  for (int i = 0; i < 16; ++i) creg[i] = 0.f;
  __syncthreads();

  const bf16* Wstr = Wh + (size_t)(n0 + l15) * 256 + quad * 8;

  for (int t = 0; t < 128; ++t) {
    const int s = d ? (127 - t) : t;
    f32x4 acc[16];
#pragma unroll
    for (int nt = 0; nt < 16; ++nt) acc[nt] = (f32x4){0.f, 0.f, 0.f, 0.f};

    // stationary part of K
#pragma unroll
    for (int kt = 0; kt < 5; ++kt) {
      short8 a = *(const short8*)&hlds[l15 * 264 + kt * 32 + quad * 8];
#pragma unroll
      for (int nt = 0; nt < 16; ++nt) acc[nt] = mfma16(a, bs[kt][nt], acc[nt]);
    }
    // streamed part of K (L2-resident after step 0)
#pragma unroll
    for (int kt = 5; kt < 8; ++kt) {
      short8 a = *(const short8*)&hlds[l15 * 264 + kt * 32 + quad * 8];
#pragma unroll
      for (int nt = 0; nt < 16; ++nt) {
        short8 bfr = *(const short8*)(Wstr + (size_t)nt * 16 * 256 + kt * 32);
        acc[nt] = mfma16(a, bfr, acc[nt]);
      }
    }

    // stage h-part gates: gst[batch][gate*256+u], pitch 1028 (2-way max = free)
#pragma unroll
    for (int nt = 0; nt < 16; ++nt) {
      int col = n0 + 16 * nt + l15;
#pragma unroll
      for (int r = 0; r < 4; ++r)
        gst[(quad * 4 + r) * 1028 + col] = clampf(acc[nt][r], 64.f);
    }
    __syncthreads();

    // epilogue: thread tid owns hidden-unit u=tid for all 16 local batches
#pragma unroll
    for (int b = 0; b < 16; ++b) {
      const int gb = b0 + b;
      const size_t xr = ((size_t)gb * 128 + s) * 1024 + tid;
      float gi = gst[b * 1028 + tid]       + X[xr];
      float gf = gst[b * 1028 + 256 + tid] + X[xr + 256];
      float gg = gst[b * 1028 + 512 + tid] + X[xr + 512];
      float go = gst[b * 1028 + 768 + tid] + X[xr + 768];
      float c = clampf(sigf(gf) * creg[b] + sigf(gi) * tanh_f(gg), 256.f);
      creg[b] = c;
      float h = clampf(sigf(go) * tanh_f(c), 4.f);
      out[((size_t)gb * 128 + s) * 512 + (size_t)d * 256 + tid] = __float2bfloat16(h);
      if (layer == 1 && d == 0 && t == 127)
        g_HID[gb * 256 + tid] = h;                     // decoder hidden0, exact f32
      hlds[b * 264 + tid] = __float2bfloat16(h);
    }
    __syncthreads();
  }
}

// ---------------------------------------------------------------------------
// Per decoder step: token select (+argmax of prev pred), hWa, energies,
// softmax, context; writes g_XIN=[emb|ctx] and g_HC[256:768]=ctx. grid=64 (b).
__global__ __launch_bounds__(256) void attn_step(int step,
                                                 const int* __restrict__ trg,
                                                 const unsigned char* __restrict__ tfm,
                                                 const float* __restrict__ dec_emb,
                                                 const float* __restrict__ Wa,  // [256][768] f32
                                                 const float* __restrict__ ba,
                                                 const float* __restrict__ vv,
                                                 const float* __restrict__ outp) // d_out f32
{
  int b = blockIdx.x, tid = threadIdx.x;
  __shared__ float sh[256], hb[256], vsh[256], es[128], red[256];
  __shared__ int ridx[256];
  __shared__ int stok;

  if (step == 1) {
    if (tid == 0) stok = trg[b * 64];
  } else {
    const float* pr = outp + (size_t)b * 640000 + (size_t)(step - 1) * 10000;
    float bv = -3.4e38f; int bi = 0;
    for (int v2 = tid; v2 < 10000; v2 += 256) {
      float pv = pr[v2];
      if (pv > bv) { bv = pv; bi = v2; }   // ascending scan: first-max kept
    }
    red[tid] = bv; ridx[tid] = bi;
    __syncthreads();
    for (int off = 128; off; off >>= 1) {
      if (tid < off) {
        float ov = red[tid + off]; int oi = ridx[tid + off];
        if (ov > red[tid] || (ov == red[tid] && oi < ridx[tid])) { red[tid] = ov; ridx[tid] = oi; }
      }
      __syncthreads();
    }
    if (tid == 0) {
      int k = step - 1;
      // true under both uint8-bool and int32-bool storage (mask is all-True)
      int tf = (int)tfm[k] | (int)tfm[4 * k];
      int tok = tf ? trg[b * 64 + k] : ridx[0];
      if (tok < 0 || tok >= 10000) tok = 0;            // defensive
      stok = tok;
    }
    __syncthreads();
  }

  sh[tid]  = g_HID[b * 256 + tid];
  vsh[tid] = vv[tid];
  __syncthreads();

  // hWa[j] + ba[j]  (first 256 cols of Wa act on hidden) — f32 weights
  {
    float acc = 0.f;
    const float* wr = Wa + (size_t)tid * 768;
    for (int k4 = 0; k4 < 256; k4 += 4) {
      float4 w4 = *(const float4*)(wr + k4);
      acc += sh[k4] * w4.x + sh[k4 + 1] * w4.y + sh[k4 + 2] * w4.z + sh[k4 + 3] * w4.w;
    }
    hb[tid] = clampf(acc + ba[tid], 64.f);
  }
  __syncthreads();

  // energies: wave w handles s = w, w+4, ...
  int wv = tid >> 6, ln = tid & 63;
  for (int s = wv; s < 128; s += 4) {
    const float* Er = g_EWA + ((size_t)b * 128 + s) * 256;
    float part = 0.f;
#pragma unroll
    for (int jj = 0; jj < 4; ++jj) {
      int j = ln + 64 * jj;
      part += tanh_f(hb[j] + Er[j]) * vsh[j];
    }
    part += __shfl_down(part, 32);
    part += __shfl_down(part, 16);
    part += __shfl_down(part, 8);
    part += __shfl_down(part, 4);
    part += __shfl_down(part, 2);
    part += __shfl_down(part, 1);
    if (ln == 0) es[s] = clampf(part, 512.f);
  }
  __syncthreads();

  // softmax over s
  red[tid] = (tid < 128) ? es[tid] : -3.4e38f;
  __syncthreads();
  for (int off = 128; off; off >>= 1) { if (tid < off) red[tid] = fmaxf(red[tid], red[tid + off]); __syncthreads(); }
  float mx = red[0];
  __syncthreads();
  float pexp = (tid < 128) ? fexp2((es[tid] - mx) * 1.44269504f) : 0.f;
  red[tid] = pexp;
  __syncthreads();
  for (int off = 128; off; off >>= 1) { if (tid < off) red[tid] += red[tid + off]; __syncthreads(); }
  float inv = frcp(red[0]);
  __syncthreads();
  if (tid < 128) es[tid] = pexp * inv;
  __syncthreads();

  // context
  float c0 = 0.f, c1 = 0.f;
  for (int s = 0; s < 128; ++s) {
    const bf16* er = g_ENC + ((size_t)b * 128 + s) * 512;
    float a = es[s];
    c0 += a * b2f(er[tid]);
    c1 += a * b2f(er[tid + 256]);
  }
  c0 = clampf(c0, 16.f);
  c1 = clampf(c1, 16.f);
  g_XIN[(size_t)b * 640 + 128 + tid] = __float2bfloat16(c0);
  g_XIN[(size_t)b * 640 + 384 + tid] = __float2bfloat16(c1);
  g_HC [(size_t)b * 768 + 256 + tid] = __float2bfloat16(c0);
  g_HC [(size_t)b * 768 + 512 + tid] = __float2bfloat16(c1);
  if (tid < 128)
    g_XIN[(size_t)b * 640 + tid] = __float2bfloat16(dec_emb[(size_t)stok * 128 + tid]);
}

// ---------------------------------------------------------------------------
// g = xin @ dWih.T + db fused with cell: c=sig(i)*tanh(g); h=sig(o)*tanh(c)
// grid = 16: block bx owns u-slice [16bx,16bx+16); wave = gate.
__global__ __launch_bounds__(256) void dec_gemm_cell(const float* __restrict__ db) {
  __shared__ float gst[64 * 68];
  const int tid = threadIdx.x;
  const int wave = tid >> 6, lane = tid & 63, l15 = lane & 15, quad = lane >> 4;
  const int u0 = blockIdx.x * 16;

  f32x4 acc[4];
#pragma unroll
  for (int mt = 0; mt < 4; ++mt) acc[mt] = (f32x4){0.f, 0.f, 0.f, 0.f};

  const bf16* Brow = g_WBF + OFF_DWIH + (size_t)(wave * 256 + u0 + l15) * 640 + quad * 8;
  for (int kt = 0; kt < 20; ++kt) {
    short8 bfr = *(const short8*)(Brow + kt * 32);
#pragma unroll
    for (int mt = 0; mt < 4; ++mt) {
      short8 a = *(const short8*)(g_XIN + (size_t)(16 * mt + l15) * 640 + kt * 32 + quad * 8);
      acc[mt] = mfma16(a, bfr, acc[mt]);
    }
  }
#pragma unroll
  for (int mt = 0; mt < 4; ++mt)
#pragma unroll
    for (int r = 0; r < 4; ++r)
      gst[(16 * mt + quad * 4 + r) * 68 + wave * 16 + l15] = clampf(acc[mt][r], 64.f);
  __syncthreads();

  for (int p = tid; p < 1024; p += 256) {
    int b = p >> 4, uu = p & 15;
    int u = u0 + uu;
    float gi = gst[b * 68 + 0  + uu] + db[u];
    float gg = gst[b * 68 + 32 + uu] + db[512 + u];
    float go = gst[b * 68 + 48 + uu] + db[768 + u];
    float c = sigf(gi) * tanh_f(gg);
    float h = clampf(sigf(go) * tanh_f(c), 4.f);
    g_HID[b * 256 + u] = h;
    g_HC[(size_t)b * 768 + u] = __float2bfloat16(h);
  }
}

// ---------------------------------------------------------------------------
__global__ __launch_bounds__(256) void zero_t0(float* __restrict__ outp) {
  int idx = blockIdx.x * 256 + threadIdx.x;        // 64*10000
  int b = idx / 10000, v = idx - b * 10000;
  outp[(size_t)b * 640000 + v] = 0.f;
}

// ---------------------------------------------------------------------------
extern "C" void kernel_launch(void* const* d_in, const int* in_sizes, int n_in,
                              void* d_out, int out_size, void* d_ws, size_t ws_size,
                              hipStream_t stream) {
  (void)in_sizes; (void)n_in; (void)out_size; (void)d_ws; (void)ws_size;

  const int*   src     = (const int*)   d_in[0];
  const int*   trg     = (const int*)   d_in[1];
  const unsigned char* tfm = (const unsigned char*) d_in[2];
  const float* enc_emb = (const float*) d_in[3];
  const float* e1f_Wih = (const float*) d_in[4];
  const float* e1f_Whh = (const float*) d_in[5];
  const float* e1f_b   = (const float*) d_in[6];
  const float* e1b_Wih = (const float*) d_in[7];
  const float* e1b_Whh = (const float*) d_in[8];
  const float* e1b_b   = (const float*) d_in[9];
  const float* e2f_Wih = (const float*) d_in[10];
  const float* e2f_Whh = (const float*) d_in[11];
  const float* e2f_b   = (const float*) d_in[12];
  const float* e2b_Wih = (const float*) d_in[13];
  const float* e2b_Whh = (const float*) d_in[14];
  const float* e2b_b   = (const float*) d_in[15];
  const float* dec_emb = (const float*) d_in[16];
  const float* Wa      = (const float*) d_in[17];
  const float* ba      = (const float*) d_in[18];
  const float* vv      = (const float*) d_in[19];
  const float* dWih    = (const float*) d_in[20];
  const float* db      = (const float*) d_in[21];
  const float* Wfc     = (const float*) d_in[22];
  const float* bfc     = (const float*) d_in[23];
  float* outp = (float*) d_out;

  // ---- weight conversion f32 -> bf16 pool ----
  cvt_w<<<128,  256, 0, stream>>>(e1f_Wih, OFF_E1F_WIH, 131072);
  cvt_w<<<128,  256, 0, stream>>>(e1b_Wih, OFF_E1B_WIH, 131072);
  cvt_w<<<512,  256, 0, stream>>>(e2f_Wih, OFF_E2F_WIH, 524288);
  cvt_w<<<512,  256, 0, stream>>>(e2b_Wih, OFF_E2B_WIH, 524288);
  cvt_w<<<256,  256, 0, stream>>>(e1f_Whh, OFF_E1F_WHH, 262144);
  cvt_w<<<256,  256, 0, stream>>>(e1b_Whh, OFF_E1B_WHH, 262144);
  cvt_w<<<256,  256, 0, stream>>>(e2f_Whh, OFF_E2F_WHH, 262144);
  cvt_w<<<256,  256, 0, stream>>>(e2b_Whh, OFF_E2B_WHH, 262144);
  cvt_w<<<640,  256, 0, stream>>>(dWih,    OFF_DWIH,    655360);
  cvt_w<<<7500, 256, 0, stream>>>(Wfc,     OFF_WFC,     7680000);
  cvt_w<<<192,  256, 0, stream>>>(Wa,      OFF_WA,      196608);

  // ---- encoder ----
  embed_k<<<1024, 256, 0, stream>>>(src, enc_emb);
  gemm_x1<<<dim3(128, 16), 256, 0, stream>>>(OFF_E1F_WIH, e1f_b, 0);
  gemm_x1<<<dim3(128, 16), 256, 0, stream>>>(OFF_E1B_WIH, e1b_b, 1);
  lstm_batch<<<8, 256, 0, stream>>>(OFF_E1F_WHH, OFF_E1B_WHH, 0);
  gemm_x2<<<dim3(128, 16), 256, 0, stream>>>(OFF_E2F_WIH, e2f_b, 0);
  gemm_x2<<<dim3(128, 16), 256, 0, stream>>>(OFF_E2B_WIH, e2b_b, 1);
  lstm_batch<<<8, 256, 0, stream>>>(OFF_E2F_WHH, OFF_E2B_WHH, 1);
  gemm_ewa<<<dim3(128, 4), 256, 0, stream>>>();
  zero_t0<<<2500, 256, 0, stream>>>(outp);

  // ---- decoder ----
  for (int i = 1; i < 64; ++i) {
    attn_step<<<64, 256, 0, stream>>>(i, trg, tfm, dec_emb, Wa, ba, vv, outp);
    dec_gemm_cell<<<16, 256, 0, stream>>>(db);
    gemm_pred<<<dim3(1, 157), 256, 0, stream>>>(bfc, outp, i);
  }
}

// Round 2
// 9435.761 us; speedup vs baseline: 1.2772x; 1.0429x over previous
//
#include <hip/hip_runtime.h>
#include <hip/hip_bf16.h>
#include <cstdint>

// ---------------------------------------------------------------------------
// Seq2Seq (B=64, S=128, T=64, V=10000, E=128, H=256).
// ALL float tensors are FLOAT32 (per reference, jnp.float32) — inputs read as
// const float*, d_out written as float*. MFMA compute in bf16 via one-time
// per-launch weight conversion into a module-global bf16 pool.
// Encoder: 2-layer biLSTM, batch-split recurrence — grid = 8 blocks
// (dir x 4 batch-groups of 16), h/c block-local, ZERO inter-block sync.
// NEW (round 2): 512 thr/block (8 waves -> 2 waves/SIMD for TLP), per-wave
// register load halved (bs[4][8]=128 VGPR stationary, kt4..7 streamed from
// L2), X preacts prefetched one step ahead into registers. Same math order.
// Decoder: 63 steps of attention + LSTMCell + V-projection (unchanged).
// ---------------------------------------------------------------------------

typedef __hip_bfloat16 bf16;
typedef __attribute__((ext_vector_type(8))) short short8;   // 8 bf16 = 4 VGPRs
typedef __attribute__((ext_vector_type(4))) float f32x4;

// ---- bf16 weight pool offsets (elements) ----------------------------------
#define OFF_E1F_WIH 0L
#define OFF_E1B_WIH 131072L
#define OFF_E2F_WIH 262144L
#define OFF_E2B_WIH 786432L
#define OFF_E1F_WHH 1310720L
#define OFF_E1B_WHH 1572864L
#define OFF_E2F_WHH 1835008L
#define OFF_E2B_WHH 2097152L
#define OFF_DWIH    2359296L
#define OFF_WFC     3014656L
#define OFF_WA      10694656L
#define WBF_TOTAL   10891264L

// ---- module-scope scratch (allocated at .so load) -------------------------
__device__ __align__(16) bf16     g_WBF[WBF_TOTAL];     // 21.8 MB bf16 weights
__device__ __align__(16) float    g_X1F[8192 * 1024];   // 32 MB gate preacts fwd
__device__ __align__(16) float    g_X1B[8192 * 1024];   // 32 MB gate preacts bwd
__device__ __align__(16) bf16     g_EMB[8192 * 128];    // 2 MB embedded src
__device__ __align__(16) bf16     g_OUT1[8192 * 512];   // 8 MB layer-1 output
__device__ __align__(16) bf16     g_ENC[8192 * 512];    // 8 MB encoder output
__device__ __align__(16) float    g_EWA[8192 * 256];    // 8 MB enc@Wa[:,H:]^T
__device__ __align__(16) float    g_HID[64 * 256];      // decoder hidden (f32)
__device__ __align__(16) bf16     g_XIN[64 * 640];      // [emb|ctx]
__device__ __align__(16) bf16     g_HC[64 * 768];       // [h|ctx]

__device__ __forceinline__ float b2f(bf16 x) { return __bfloat162float(x); }
__device__ __forceinline__ float fexp2(float x) { return __builtin_amdgcn_exp2f(x); }
__device__ __forceinline__ float frcp(float x)  { return __builtin_amdgcn_rcpf(x); }
__device__ __forceinline__ float clampf(float x, float L) {
  return fminf(fmaxf(x, -L), L);       // NaN -> -L
}
__device__ __forceinline__ float sigf(float x) {
  x = clampf(x, 30.f);
  return frcp(1.f + fexp2(-1.44269504f * x));
}
__device__ __forceinline__ float tanh_f(float x) {
  x = clampf(x, 15.f);
  float e = fexp2(2.885390082f * x);          // e^(2x)
  return (e - 1.f) * frcp(e + 1.f);
}
__device__ __forceinline__ f32x4 mfma16(short8 a, short8 b, f32x4 c) {
  return __builtin_amdgcn_mfma_f32_16x16x32_bf16(a, b, c, 0, 0, 0);
}

// ---------------------------------------------------------------------------
// f32 -> bf16 weight conversion into pool (n multiple of 4)
__global__ __launch_bounds__(256) void cvt_w(const float* __restrict__ src,
                                             long off, int n) {
  int i = (blockIdx.x * 256 + threadIdx.x) * 4;
  if (i >= n) return;
  float4 v = *(const float4*)(src + i);
  bf16* d = g_WBF + off + i;
  d[0] = __float2bfloat16(v.x);
  d[1] = __float2bfloat16(v.y);
  d[2] = __float2bfloat16(v.z);
  d[3] = __float2bfloat16(v.w);
}

// emb[b*S+s][e] = enc_emb[src[b][s]][e]  (f32 table -> bf16)
__global__ __launch_bounds__(256) void embed_k(const int* __restrict__ src,
                                               const float* __restrict__ tab) {
  int i4 = (blockIdx.x * 256 + threadIdx.x) * 4;      // 8192*128 elems
  int row = i4 >> 7, e = i4 & 127;
  int tok = src[row];
  if (tok < 0 || tok >= 10000) tok = 0;               // defensive
  float4 v = *(const float4*)&tab[(size_t)tok * 128 + e];
  bf16* d = &g_EMB[(size_t)row * 128 + e];
  d[0] = __float2bfloat16(v.x);
  d[1] = __float2bfloat16(v.y);
  d[2] = __float2bfloat16(v.z);
  d[3] = __float2bfloat16(v.w);
}

// ---------------------------------------------------------------------------
// C[M,N] = A[M,K] @ W[N,K]^T + bias(f32).  Writes f32 (Cf), clamped.
// grid = (M/64, ceil(N/64)); block 256 = 4 waves; wave w: rows [bx*64+16w,+16).
__device__ __forceinline__ void gemm_core(const bf16* __restrict__ A, int lda,
                                          const bf16* __restrict__ W, int ldw, int wcol,
                                          const float* __restrict__ bias,
                                          float* __restrict__ Cf,
                                          long ldc, int N, int K, float clampL) {
  const int wave = threadIdx.x >> 6, lane = threadIdx.x & 63;
  const int l15 = lane & 15, quad = lane >> 4;
  const int m0 = blockIdx.x * 64 + wave * 16;
  const int n0 = blockIdx.y * 64;

  f32x4 acc[4];
#pragma unroll
  for (int j = 0; j < 4; ++j) acc[j] = (f32x4){0.f, 0.f, 0.f, 0.f};

  const bf16* Arow = A + (size_t)(m0 + l15) * lda + quad * 8;
  for (int k = 0; k < K; k += 32) {
    short8 a = *(const short8*)(Arow + k);
#pragma unroll
    for (int j = 0; j < 4; ++j) {
      int n = n0 + 16 * j + l15;
      short8 bfr = (short8){0, 0, 0, 0, 0, 0, 0, 0};
      if (n < N) bfr = *(const short8*)(W + (size_t)n * ldw + wcol + k + quad * 8);
      acc[j] = mfma16(a, bfr, acc[j]);
    }
  }
#pragma unroll
  for (int j = 0; j < 4; ++j) {
    int n = n0 + 16 * j + l15;
    if (n >= N) continue;
    float bv = bias ? bias[n] : 0.f;
#pragma unroll
    for (int r = 0; r < 4; ++r) {
      int m = m0 + quad * 4 + r;
      Cf[(size_t)m * ldc + n] = clampf(acc[j][r] + bv, clampL);
    }
  }
}

// layer-1 input GEMM: g_EMB[8192,128] @ W[1024,128]^T -> g_X1F/g_X1B (f32)
__global__ __launch_bounds__(256) void gemm_x1(long offW, const float* __restrict__ bias,
                                               int bwd) {
  gemm_core(g_EMB, 128, g_WBF + offW, 128, 0, bias, bwd ? g_X1B : g_X1F,
            1024, 1024, 128, 64.f);
}
// layer-2 input GEMM: g_OUT1[8192,512] @ W[1024,512]^T -> g_X1F/g_X1B (reuse)
__global__ __launch_bounds__(256) void gemm_x2(long offW, const float* __restrict__ bias,
                                               int bwd) {
  gemm_core(g_OUT1, 512, g_WBF + offW, 512, 0, bias, bwd ? g_X1B : g_X1F,
            1024, 1024, 512, 64.f);
}
// attention precompute: g_ENC[8192,512] @ Wa[:,256:768]^T -> g_EWA (f32)
__global__ __launch_bounds__(256) void gemm_ewa() {
  gemm_core(g_ENC, 512, g_WBF + OFF_WA, 768, 256, nullptr, g_EWA, 256, 256, 512, 64.f);
}
// prediction: g_HC[64,768] @ Wfc[10000,768]^T + bfc -> outp+step*10000 (f32)
__global__ __launch_bounds__(256) void gemm_pred(const float* __restrict__ bfc,
                                                 float* __restrict__ outp, int step) {
  gemm_core(g_HC, 768, g_WBF + OFF_WFC, 768, 0, bfc, outp + (size_t)step * 10000,
            640000, 10000, 768, 512.f);
}

// ---------------------------------------------------------------------------
// Batch-split persistent biLSTM layer. grid = 8: dir d = bx&1, batch-group
// bg = bx>>1 (batches [16bg, 16bg+16)). Block = 512 thr = 8 waves; wave w
// owns 128 gate-columns [128w, 128w+128).  2 waves/SIMD for latency hiding.
// h (bf16 in LDS) and c (registers) are block-local -> NO inter-block sync.
// Whh: kt 0..3 (K-cols 0..127) register-stationary (32 short8 = 128 VGPR),
// kt 4..7 streamed from L2 each step (32 KB/wave/step).
// X preacts for step t+1 prefetched into xreg during step t's epilogue.
// Gate math path (k-order, clamps) identical to previous kernel ->
// bitwise-identical h/c trajectory.
__global__ __launch_bounds__(512, 2) void lstm_batch(long offWhf, long offWhb,
                                                     int layer) {
  const int bx = blockIdx.x;
  const int d = bx & 1, bg = bx >> 1;
  const int b0 = bg * 16;
  const float* __restrict__ X  = d ? g_X1B : g_X1F;
  const bf16*  __restrict__ Wh = g_WBF + (d ? offWhb : offWhf);
  bf16* __restrict__ out = layer ? g_ENC : g_OUT1;     // [64][128][512]

  __shared__ __align__(16) bf16 hlds[16 * 264];        // h tile, pitch 264
  __shared__ float gst[16 * 1028];                     // gates staging (f32)

  const int tid = threadIdx.x;
  const int wave = tid >> 6, lane = tid & 63, l15 = lane & 15, quad = lane >> 4;
  const int n0 = wave * 128;                           // wave -> 128 gate cols
  const int u  = tid & 255;                            // epilogue: hidden unit
  const int bh = tid >> 8;                             // epilogue: batch half

  // ---- stationary B frags: kt 0..3, nt 0..7 (128 VGPRs) ----
  short8 bs[4][8];
#pragma unroll
  for (int kt = 0; kt < 4; ++kt)
#pragma unroll
    for (int nt = 0; nt < 8; ++nt)
      bs[kt][nt] = *(const short8*)(Wh + (size_t)(n0 + 16 * nt + l15) * 256 +
                                    kt * 32 + quad * 8);

  for (int i = tid; i < 16 * 264; i += 512) hlds[i] = __float2bfloat16(0.f);
  float creg[8];
#pragma unroll
  for (int i = 0; i < 8; ++i) creg[i] = 0.f;

  // ---- prefetch X for step 0 ----
  float xreg[32];                                      // [8 batches][4 gates]
  {
    const int s0 = d ? 127 : 0;
#pragma unroll
    for (int j = 0; j < 8; ++j) {
      const size_t xr = ((size_t)(b0 + bh * 8 + j) * 128 + s0) * 1024 + u;
#pragma unroll
      for (int g = 0; g < 4; ++g) xreg[j * 4 + g] = X[xr + g * 256];
    }
  }
  __syncthreads();

  const bf16* Wstr = Wh + (size_t)(n0 + l15) * 256 + quad * 8;

  for (int t = 0; t < 128; ++t) {
    const int s = d ? (127 - t) : t;
    f32x4 acc[8];
#pragma unroll
    for (int nt = 0; nt < 8; ++nt) acc[nt] = (f32x4){0.f, 0.f, 0.f, 0.f};

    // stationary part of K
#pragma unroll
    for (int kt = 0; kt < 4; ++kt) {
      short8 a = *(const short8*)&hlds[l15 * 264 + kt * 32 + quad * 8];
#pragma unroll
      for (int nt = 0; nt < 8; ++nt) acc[nt] = mfma16(a, bs[kt][nt], acc[nt]);
    }
    // streamed part of K (L2-resident after step 0)
#pragma unroll
    for (int kt = 4; kt < 8; ++kt) {
      short8 a = *(const short8*)&hlds[l15 * 264 + kt * 32 + quad * 8];
#pragma unroll
      for (int nt = 0; nt < 8; ++nt) {
        short8 bfr = *(const short8*)(Wstr + (size_t)nt * 16 * 256 + kt * 32);
        acc[nt] = mfma16(a, bfr, acc[nt]);
      }
    }

    // stage h-part gates: gst[batch][col], pitch 1028 (2-way max = free)
#pragma unroll
    for (int nt = 0; nt < 8; ++nt) {
      int col = n0 + 16 * nt + l15;
#pragma unroll
      for (int r = 0; r < 4; ++r)
        gst[(quad * 4 + r) * 1028 + col] = clampf(acc[nt][r], 64.f);
    }
    __syncthreads();

    // epilogue: thread owns unit u for 8 batches (bh*8 .. bh*8+7)
#pragma unroll
    for (int j = 0; j < 8; ++j) {
      const int b = bh * 8 + j;
      const int gb = b0 + b;
      float gi = gst[b * 1028 + u]       + xreg[j * 4 + 0];
      float gf = gst[b * 1028 + 256 + u] + xreg[j * 4 + 1];
      float gg = gst[b * 1028 + 512 + u] + xreg[j * 4 + 2];
      float go = gst[b * 1028 + 768 + u] + xreg[j * 4 + 3];
      float c = clampf(sigf(gf) * creg[j] + sigf(gi) * tanh_f(gg), 256.f);
      creg[j] = c;
      float h = clampf(sigf(go) * tanh_f(c), 4.f);
      out[((size_t)gb * 128 + s) * 512 + (size_t)d * 256 + u] = __float2bfloat16(h);
      if (layer == 1 && d == 0 && t == 127)
        g_HID[gb * 256 + u] = h;                       // decoder hidden0, exact f32
      hlds[b * 264 + u] = __float2bfloat16(h);
    }

    // prefetch X for step t+1 (latency hides under next MFMA phase)
    {
      const int tn = (t < 127) ? (t + 1) : t;
      const int sn = d ? (127 - tn) : tn;
#pragma unroll
      for (int j = 0; j < 8; ++j) {
        const size_t xr = ((size_t)(b0 + bh * 8 + j) * 128 + sn) * 1024 + u;
#pragma unroll
        for (int g = 0; g < 4; ++g) xreg[j * 4 + g] = X[xr + g * 256];
      }
    }
    __syncthreads();
  }
}

// ---------------------------------------------------------------------------
// Per decoder step: token select (+argmax of prev pred), hWa, energies,
// softmax, context; writes g_XIN=[emb|ctx] and g_HC[256:768]=ctx. grid=64 (b).
__global__ __launch_bounds__(256) void attn_step(int step,
                                                 const int* __restrict__ trg,
                                                 const unsigned char* __restrict__ tfm,
                                                 const float* __restrict__ dec_emb,
                                                 const float* __restrict__ Wa,  // [256][768] f32
                                                 const float* __restrict__ ba,
                                                 const float* __restrict__ vv,
                                                 const float* __restrict__ outp) // d_out f32
{
  int b = blockIdx.x, tid = threadIdx.x;
  __shared__ float sh[256], hb[256], vsh[256], es[128], red[256];
  __shared__ int ridx[256];
  __shared__ int stok;

  if (step == 1) {
    if (tid == 0) stok = trg[b * 64];
  } else {
    const float* pr = outp + (size_t)b * 640000 + (size_t)(step - 1) * 10000;
    float bv = -3.4e38f; int bi = 0;
    for (int v2 = tid; v2 < 10000; v2 += 256) {
      float pv = pr[v2];
      if (pv > bv) { bv = pv; bi = v2; }   // ascending scan: first-max kept
    }
    red[tid] = bv; ridx[tid] = bi;
    __syncthreads();
    for (int off = 128; off; off >>= 1) {
      if (tid < off) {
        float ov = red[tid + off]; int oi = ridx[tid + off];
        if (ov > red[tid] || (ov == red[tid] && oi < ridx[tid])) { red[tid] = ov; ridx[tid] = oi; }
      }
      __syncthreads();
    }
    if (tid == 0) {
      int k = step - 1;
      // true under both uint8-bool and int32-bool storage (mask is all-True)
      int tf = (int)tfm[k] | (int)tfm[4 * k];
      int tok = tf ? trg[b * 64 + k] : ridx[0];
      if (tok < 0 || tok >= 10000) tok = 0;            // defensive
      stok = tok;
    }
    __syncthreads();
  }

  sh[tid]  = g_HID[b * 256 + tid];
  vsh[tid] = vv[tid];
  __syncthreads();

  // hWa[j] + ba[j]  (first 256 cols of Wa act on hidden) — f32 weights
  {
    float acc = 0.f;
    const float* wr = Wa + (size_t)tid * 768;
    for (int k4 = 0; k4 < 256; k4 += 4) {
      float4 w4 = *(const float4*)(wr + k4);
      acc += sh[k4] * w4.x + sh[k4 + 1] * w4.y + sh[k4 + 2] * w4.z + sh[k4 + 3] * w4.w;
    }
    hb[tid] = clampf(acc + ba[tid], 64.f);
  }
  __syncthreads();

  // energies: wave w handles s = w, w+4, ...
  int wv = tid >> 6, ln = tid & 63;
  for (int s = wv; s < 128; s += 4) {
    const float* Er = g_EWA + ((size_t)b * 128 + s) * 256;
    float part = 0.f;
#pragma unroll
    for (int jj = 0; jj < 4; ++jj) {
      int j = ln + 64 * jj;
      part += tanh_f(hb[j] + Er[j]) * vsh[j];
    }
    part += __shfl_down(part, 32);
    part += __shfl_down(part, 16);
    part += __shfl_down(part, 8);
    part += __shfl_down(part, 4);
    part += __shfl_down(part, 2);
    part += __shfl_down(part, 1);
    if (ln == 0) es[s] = clampf(part, 512.f);
  }
  __syncthreads();

  // softmax over s
  red[tid] = (tid < 128) ? es[tid] : -3.4e38f;
  __syncthreads();
  for (int off = 128; off; off >>= 1) { if (tid < off) red[tid] = fmaxf(red[tid], red[tid + off]); __syncthreads(); }
  float mx = red[0];
  __syncthreads();
  float pexp = (tid < 128) ? fexp2((es[tid] - mx) * 1.44269504f) : 0.f;
  red[tid] = pexp;
  __syncthreads();
  for (int off = 128; off; off >>= 1) { if (tid < off) red[tid] += red[tid + off]; __syncthreads(); }
  float inv = frcp(red[0]);
  __syncthreads();
  if (tid < 128) es[tid] = pexp * inv;
  __syncthreads();

  // context
  float c0 = 0.f, c1 = 0.f;
  for (int s = 0; s < 128; ++s) {
    const bf16* er = g_ENC + ((size_t)b * 128 + s) * 512;
    float a = es[s];
    c0 += a * b2f(er[tid]);
    c1 += a * b2f(er[tid + 256]);
  }
  c0 = clampf(c0, 16.f);
  c1 = clampf(c1, 16.f);
  g_XIN[(size_t)b * 640 + 128 + tid] = __float2bfloat16(c0);
  g_XIN[(size_t)b * 640 + 384 + tid] = __float2bfloat16(c1);
  g_HC [(size_t)b * 768 + 256 + tid] = __float2bfloat16(c0);
  g_HC [(size_t)b * 768 + 512 + tid] = __float2bfloat16(c1);
  if (tid < 128)
    g_XIN[(size_t)b * 640 + tid] = __float2bfloat16(dec_emb[(size_t)stok * 128 + tid]);
}

// ---------------------------------------------------------------------------
// g = xin @ dWih.T + db fused with cell: c=sig(i)*tanh(g); h=sig(o)*tanh(c)
// grid = 16: block bx owns u-slice [16bx,16bx+16); wave = gate.
__global__ __launch_bounds__(256) void dec_gemm_cell(const float* __restrict__ db) {
  __shared__ float gst[64 * 68];
  const int tid = threadIdx.x;
  const int wave = tid >> 6, lane = tid & 63, l15 = lane & 15, quad = lane >> 4;
  const int u0 = blockIdx.x * 16;

  f32x4 acc[4];
#pragma unroll
  for (int mt = 0; mt < 4; ++mt) acc[mt] = (f32x4){0.f, 0.f, 0.f, 0.f};

  const bf16* Brow = g_WBF + OFF_DWIH + (size_t)(wave * 256 + u0 + l15) * 640 + quad * 8;
  for (int kt = 0; kt < 20; ++kt) {
    short8 bfr = *(const short8*)(Brow + kt * 32);
#pragma unroll
    for (int mt = 0; mt < 4; ++mt) {
      short8 a = *(const short8*)(g_XIN + (size_t)(16 * mt + l15) * 640 + kt * 32 + quad * 8);
      acc[mt] = mfma16(a, bfr, acc[mt]);
    }
  }
#pragma unroll
  for (int mt = 0; mt < 4; ++mt)
#pragma unroll
    for (int r = 0; r < 4; ++r)
      gst[(16 * mt + quad * 4 + r) * 68 + wave * 16 + l15] = clampf(acc[mt][r], 64.f);
  __syncthreads();

  for (int p = tid; p < 1024; p += 256) {
    int b = p >> 4, uu = p & 15;
    int u = u0 + uu;
    float gi = gst[b * 68 + 0  + uu] + db[u];
    float gg = gst[b * 68 + 32 + uu] + db[512 + u];
    float go = gst[b * 68 + 48 + uu] + db[768 + u];
    float c = sigf(gi) * tanh_f(gg);
    float h = clampf(sigf(go) * tanh_f(c), 4.f);
    g_HID[b * 256 + u] = h;
    g_HC[(size_t)b * 768 + u] = __float2bfloat16(h);
  }
}

// ---------------------------------------------------------------------------
__global__ __launch_bounds__(256) void zero_t0(float* __restrict__ outp) {
  int idx = blockIdx.x * 256 + threadIdx.x;        // 64*10000
  int b = idx / 10000, v = idx - b * 10000;
  outp[(size_t)b * 640000 + v] = 0.f;
}

// ---------------------------------------------------------------------------
extern "C" void kernel_launch(void* const* d_in, const int* in_sizes, int n_in,
                              void* d_out, int out_size, void* d_ws, size_t ws_size,
                              hipStream_t stream) {
  (void)in_sizes; (void)n_in; (void)out_size; (void)d_ws; (void)ws_size;

  const int*   src     = (const int*)   d_in[0];
  const int*   trg     = (const int*)   d_in[1];
  const unsigned char* tfm = (const unsigned char*) d_in[2];
  const float* enc_emb = (const float*) d_in[3];
  const float* e1f_Wih = (const float*) d_in[4];
  const float* e1f_Whh = (const float*) d_in[5];
  const float* e1f_b   = (const float*) d_in[6];
  const float* e1b_Wih = (const float*) d_in[7];
  const float* e1b_Whh = (const float*) d_in[8];
  const float* e1b_b   = (const float*) d_in[9];
  const float* e2f_Wih = (const float*) d_in[10];
  const float* e2f_Whh = (const float*) d_in[11];
  const float* e2f_b   = (const float*) d_in[12];
  const float* e2b_Wih = (const float*) d_in[13];
  const float* e2b_Whh = (const float*) d_in[14];
  const float* e2b_b   = (const float*) d_in[15];
  const float* dec_emb = (const float*) d_in[16];
  const float* Wa      = (const float*) d_in[17];
  const float* ba      = (const float*) d_in[18];
  const float* vv      = (const float*) d_in[19];
  const float* dWih    = (const float*) d_in[20];
  const float* db      = (const float*) d_in[21];
  const float* Wfc     = (const float*) d_in[22];
  const float* bfc     = (const float*) d_in[23];
  float* outp = (float*) d_out;

  // ---- weight conversion f32 -> bf16 pool ----
  cvt_w<<<128,  256, 0, stream>>>(e1f_Wih, OFF_E1F_WIH, 131072);
  cvt_w<<<128,  256, 0, stream>>>(e1b_Wih, OFF_E1B_WIH, 131072);
  cvt_w<<<512,  256, 0, stream>>>(e2f_Wih, OFF_E2F_WIH, 524288);
  cvt_w<<<512,  256, 0, stream>>>(e2b_Wih, OFF_E2B_WIH, 524288);
  cvt_w<<<256,  256, 0, stream>>>(e1f_Whh, OFF_E1F_WHH, 262144);
  cvt_w<<<256,  256, 0, stream>>>(e1b_Whh, OFF_E1B_WHH, 262144);
  cvt_w<<<256,  256, 0, stream>>>(e2f_Whh, OFF_E2F_WHH, 262144);
  cvt_w<<<256,  256, 0, stream>>>(e2b_Whh, OFF_E2B_WHH, 262144);
  cvt_w<<<640,  256, 0, stream>>>(dWih,    OFF_DWIH,    655360);
  cvt_w<<<7500, 256, 0, stream>>>(Wfc,     OFF_WFC,     7680000);
  cvt_w<<<192,  256, 0, stream>>>(Wa,      OFF_WA,      196608);

  // ---- encoder ----
  embed_k<<<1024, 256, 0, stream>>>(src, enc_emb);
  gemm_x1<<<dim3(128, 16), 256, 0, stream>>>(OFF_E1F_WIH, e1f_b, 0);
  gemm_x1<<<dim3(128, 16), 256, 0, stream>>>(OFF_E1B_WIH, e1b_b, 1);
  lstm_batch<<<8, 512, 0, stream>>>(OFF_E1F_WHH, OFF_E1B_WHH, 0);
  gemm_x2<<<dim3(128, 16), 256, 0, stream>>>(OFF_E2F_WIH, e2f_b, 0);
  gemm_x2<<<dim3(128, 16), 256, 0, stream>>>(OFF_E2B_WIH, e2b_b, 1);
  lstm_batch<<<8, 512, 0, stream>>>(OFF_E2F_WHH, OFF_E2B_WHH, 1);
  gemm_ewa<<<dim3(128, 4), 256, 0, stream>>>();
  zero_t0<<<2500, 256, 0, stream>>>(outp);

  // ---- decoder ----
  for (int i = 1; i < 64; ++i) {
    attn_step<<<64, 256, 0, stream>>>(i, trg, tfm, dec_emb, Wa, ba, vv, outp);
    dec_gemm_cell<<<16, 256, 0, stream>>>(db);
    gemm_pred<<<dim3(1, 157), 256, 0, stream>>>(bfc, outp, i);
  }
}

// Round 3
// 7691.545 us; speedup vs baseline: 1.5669x; 1.2268x over previous
//
#include <hip/hip_runtime.h>
#include <hip/hip_bf16.h>
#include <cstdint>

// ---------------------------------------------------------------------------
// Seq2Seq (B=64, S=128, T=64, V=10000, E=128, H=256).
// ALL float tensors are FLOAT32 (per reference, jnp.float32) — inputs read as
// const float*, d_out written as float*. MFMA compute in bf16 via one-time
// per-launch weight conversion into a module-global bf16 pool.
// Encoder: 2-layer biLSTM, batch-split recurrence — grid = 8 blocks
// (dir x 4 batch-groups of 16), h/c block-local, ZERO inter-block sync.
// Round 3: per-wave column split covers all 4 gates (32 cols each) so the
// cell epilogue is register-only (no gst staging, no extra barrier).
// Whh: kt0..3 register-stationary, kt4..5 cached in LDS, kt6..7 streamed
// from L2. X preacts gate-interleaved [row][u][4] -> 8 float4 loads/step,
// prefetched one step ahead. h double-buffered in LDS -> 1 barrier/step.
// Decoder: 63 steps of attention + LSTMCell + V-projection (unchanged).
// ---------------------------------------------------------------------------

typedef __hip_bfloat16 bf16;
typedef __attribute__((ext_vector_type(8))) short short8;   // 8 bf16 = 4 VGPRs
typedef __attribute__((ext_vector_type(4))) float f32x4;

// ---- bf16 weight pool offsets (elements) ----------------------------------
#define OFF_E1F_WIH 0L
#define OFF_E1B_WIH 131072L
#define OFF_E2F_WIH 262144L
#define OFF_E2B_WIH 786432L
#define OFF_E1F_WHH 1310720L
#define OFF_E1B_WHH 1572864L
#define OFF_E2F_WHH 1835008L
#define OFF_E2B_WHH 2097152L
#define OFF_DWIH    2359296L
#define OFF_WFC     3014656L
#define OFF_WA      10694656L
#define WBF_TOTAL   10891264L

// ---- module-scope scratch (allocated at .so load) -------------------------
__device__ __align__(16) bf16     g_WBF[WBF_TOTAL];     // 21.8 MB bf16 weights
__device__ __align__(16) float    g_X1F[8192 * 1024];   // 32 MB preacts fwd [row][u][4]
__device__ __align__(16) float    g_X1B[8192 * 1024];   // 32 MB preacts bwd [row][u][4]
__device__ __align__(16) bf16     g_EMB[8192 * 128];    // 2 MB embedded src
__device__ __align__(16) bf16     g_OUT1[8192 * 512];   // 8 MB layer-1 output
__device__ __align__(16) bf16     g_ENC[8192 * 512];    // 8 MB encoder output
__device__ __align__(16) float    g_EWA[8192 * 256];    // 8 MB enc@Wa[:,H:]^T
__device__ __align__(16) float    g_HID[64 * 256];      // decoder hidden (f32)
__device__ __align__(16) bf16     g_XIN[64 * 640];      // [emb|ctx]
__device__ __align__(16) bf16     g_HC[64 * 768];       // [h|ctx]

__device__ __forceinline__ float b2f(bf16 x) { return __bfloat162float(x); }
__device__ __forceinline__ float fexp2(float x) { return __builtin_amdgcn_exp2f(x); }
__device__ __forceinline__ float frcp(float x)  { return __builtin_amdgcn_rcpf(x); }
__device__ __forceinline__ float clampf(float x, float L) {
  return fminf(fmaxf(x, -L), L);       // NaN -> -L
}
__device__ __forceinline__ float sigf(float x) {
  x = clampf(x, 30.f);
  return frcp(1.f + fexp2(-1.44269504f * x));
}
__device__ __forceinline__ float tanh_f(float x) {
  x = clampf(x, 15.f);
  float e = fexp2(2.885390082f * x);          // e^(2x)
  return (e - 1.f) * frcp(e + 1.f);
}
__device__ __forceinline__ f32x4 mfma16(short8 a, short8 b, f32x4 c) {
  return __builtin_amdgcn_mfma_f32_16x16x32_bf16(a, b, c, 0, 0, 0);
}

// ---------------------------------------------------------------------------
// f32 -> bf16 weight conversion into pool (n multiple of 4)
__global__ __launch_bounds__(256) void cvt_w(const float* __restrict__ src,
                                             long off, int n) {
  int i = (blockIdx.x * 256 + threadIdx.x) * 4;
  if (i >= n) return;
  float4 v = *(const float4*)(src + i);
  bf16* d = g_WBF + off + i;
  d[0] = __float2bfloat16(v.x);
  d[1] = __float2bfloat16(v.y);
  d[2] = __float2bfloat16(v.z);
  d[3] = __float2bfloat16(v.w);
}

// emb[b*S+s][e] = enc_emb[src[b][s]][e]  (f32 table -> bf16)
__global__ __launch_bounds__(256) void embed_k(const int* __restrict__ src,
                                               const float* __restrict__ tab) {
  int i4 = (blockIdx.x * 256 + threadIdx.x) * 4;      // 8192*128 elems
  int row = i4 >> 7, e = i4 & 127;
  int tok = src[row];
  if (tok < 0 || tok >= 10000) tok = 0;               // defensive
  float4 v = *(const float4*)&tab[(size_t)tok * 128 + e];
  bf16* d = &g_EMB[(size_t)row * 128 + e];
  d[0] = __float2bfloat16(v.x);
  d[1] = __float2bfloat16(v.y);
  d[2] = __float2bfloat16(v.z);
  d[3] = __float2bfloat16(v.w);
}

// ---------------------------------------------------------------------------
// C[M,N] = A[M,K] @ W[N,K]^T + bias(f32).  Writes f32 (Cf), clamped.
// xg=1: gate-interleaved write Cf[m*1024 + (n&255)*4 + (n>>8)] (for X preacts).
// grid = (M/64, ceil(N/64)); block 256 = 4 waves; wave w: rows [bx*64+16w,+16).
__device__ __forceinline__ void gemm_core(const bf16* __restrict__ A, int lda,
                                          const bf16* __restrict__ W, int ldw, int wcol,
                                          const float* __restrict__ bias,
                                          float* __restrict__ Cf,
                                          long ldc, int N, int K, float clampL,
                                          int xg) {
  const int wave = threadIdx.x >> 6, lane = threadIdx.x & 63;
  const int l15 = lane & 15, quad = lane >> 4;
  const int m0 = blockIdx.x * 64 + wave * 16;
  const int n0 = blockIdx.y * 64;

  f32x4 acc[4];
#pragma unroll
  for (int j = 0; j < 4; ++j) acc[j] = (f32x4){0.f, 0.f, 0.f, 0.f};

  const bf16* Arow = A + (size_t)(m0 + l15) * lda + quad * 8;
  for (int k = 0; k < K; k += 32) {
    short8 a = *(const short8*)(Arow + k);
#pragma unroll
    for (int j = 0; j < 4; ++j) {
      int n = n0 + 16 * j + l15;
      short8 bfr = (short8){0, 0, 0, 0, 0, 0, 0, 0};
      if (n < N) bfr = *(const short8*)(W + (size_t)n * ldw + wcol + k + quad * 8);
      acc[j] = mfma16(a, bfr, acc[j]);
    }
  }
#pragma unroll
  for (int j = 0; j < 4; ++j) {
    int n = n0 + 16 * j + l15;
    if (n >= N) continue;
    float bv = bias ? bias[n] : 0.f;
#pragma unroll
    for (int r = 0; r < 4; ++r) {
      int m = m0 + quad * 4 + r;
      size_t idx = xg ? ((size_t)m * 1024 + (size_t)(n & 255) * 4 + (n >> 8))
                      : ((size_t)m * ldc + n);
      Cf[idx] = clampf(acc[j][r] + bv, clampL);
    }
  }
}

// layer-1 input GEMM: g_EMB[8192,128] @ W[1024,128]^T -> g_X1F/g_X1B (f32)
__global__ __launch_bounds__(256) void gemm_x1(long offW, const float* __restrict__ bias,
                                               int bwd) {
  gemm_core(g_EMB, 128, g_WBF + offW, 128, 0, bias, bwd ? g_X1B : g_X1F,
            1024, 1024, 128, 64.f, 1);
}
// layer-2 input GEMM: g_OUT1[8192,512] @ W[1024,512]^T -> g_X1F/g_X1B (reuse)
__global__ __launch_bounds__(256) void gemm_x2(long offW, const float* __restrict__ bias,
                                               int bwd) {
  gemm_core(g_OUT1, 512, g_WBF + offW, 512, 0, bias, bwd ? g_X1B : g_X1F,
            1024, 1024, 512, 64.f, 1);
}
// attention precompute: g_ENC[8192,512] @ Wa[:,256:768]^T -> g_EWA (f32)
__global__ __launch_bounds__(256) void gemm_ewa() {
  gemm_core(g_ENC, 512, g_WBF + OFF_WA, 768, 256, nullptr, g_EWA, 256, 256, 512,
            64.f, 0);
}
// prediction: g_HC[64,768] @ Wfc[10000,768]^T + bfc -> outp+step*10000 (f32)
__global__ __launch_bounds__(256) void gemm_pred(const float* __restrict__ bfc,
                                                 float* __restrict__ outp, int step) {
  gemm_core(g_HC, 768, g_WBF + OFF_WFC, 768, 0, bfc, outp + (size_t)step * 10000,
            640000, 10000, 768, 512.f, 0);
}

// ---------------------------------------------------------------------------
// Batch-split persistent biLSTM layer. grid = 8: dir d = bx&1, batch-group
// bg = bx>>1 (batches [16bg, 16bg+16)). Block = 512 thr = 8 waves.
// Column split: nt -> gate = nt>>1, colbase = (nt>>1)*256 + 32*wave + 16*(nt&1)
// so each lane's acc holds ALL 4 gates for its cells (u = 32w+16h2+l15,
// b = quad*4+r) -> register-only epilogue, no staging LDS.
// Whh: kt0..3 stationary regs (bs[4][8] = 128 VGPR), kt4..5 in LDS (128 KB,
// loaded once), kt6..7 streamed from L2 (128 KB/block/step).
// h double-buffered in LDS -> one barrier per step.
__global__ __launch_bounds__(512, 2) void lstm_batch(long offWhf, long offWhb,
                                                     int layer) {
  const int bx = blockIdx.x;
  const int d = bx & 1, bg = bx >> 1;
  const int b0 = bg * 16;
  const float* __restrict__ X  = d ? g_X1B : g_X1F;    // [8192][256][4] gate-ilv
  const bf16*  __restrict__ Wh = g_WBF + (d ? offWhb : offWhf);
  bf16* __restrict__ out = layer ? g_ENC : g_OUT1;     // [64][128][512]

  __shared__ __align__(16) bf16 hlds[2][16 * 264];     // h double buffer
  __shared__ __align__(16) bf16 wlds[8192 * 8];        // Whh kt4..5 (128 KB)

  const int tid = threadIdx.x;
  const int wave = tid >> 6, lane = tid & 63, l15 = lane & 15, quad = lane >> 4;

  // ---- stationary B frags kt0..3: cols (nt>>1)*256 + 32*wave + 16*(nt&1) ----
  short8 bs[4][8];
#pragma unroll
  for (int nt = 0; nt < 8; ++nt) {
    const int colbase = (nt >> 1) * 256 + 32 * wave + 16 * (nt & 1);
#pragma unroll
    for (int kt = 0; kt < 4; ++kt)
      bs[kt][nt] = *(const short8*)(Wh + (size_t)(colbase + l15) * 256 +
                                    kt * 32 + quad * 8);
  }

  // ---- LDS cache of Whh kt4..5: unit (w,nt,kt2,lane) -> 16B each ----
  for (int it = 0; it < 16; ++it) {
    const int uid = tid * 16 + it;                     // 0..8191
    const int l = uid & 63, kt2 = (uid >> 6) & 1;
    const int nt = (uid >> 7) & 7, w = uid >> 10;
    const int colbase = (nt >> 1) * 256 + 32 * w + 16 * (nt & 1);
    short8 v = *(const short8*)(Wh + (size_t)(colbase + (l & 15)) * 256 +
                                (4 + kt2) * 32 + (l >> 4) * 8);
    *(short8*)&wlds[(size_t)uid * 8] = v;
  }

  // ---- streamed row bases for kt6..7 ----
  const bf16* Wrow[8];
#pragma unroll
  for (int nt = 0; nt < 8; ++nt) {
    const int colbase = (nt >> 1) * 256 + 32 * wave + 16 * (nt & 1);
    Wrow[nt] = Wh + (size_t)(colbase + l15) * 256 + quad * 8;
  }

  for (int i = tid; i < 2 * 16 * 264; i += 512)
    ((bf16*)hlds)[i] = __float2bfloat16(0.f);

  float creg[8];
#pragma unroll
  for (int i = 0; i < 8; ++i) creg[i] = 0.f;

  // ---- prefetch X (gate-interleaved float4) for step 0 ----
  float4 xg[8];                                        // [h2][r]
  {
    const int s0 = d ? 127 : 0;
#pragma unroll
    for (int h2 = 0; h2 < 2; ++h2) {
      const int u = 32 * wave + 16 * h2 + l15;
#pragma unroll
      for (int r = 0; r < 4; ++r) {
        const int gb = b0 + quad * 4 + r;
        xg[h2 * 4 + r] = *(const float4*)&X[(((size_t)gb * 128 + s0) * 256 + u) * 4];
      }
    }
  }
  __syncthreads();

  int p = 0;
  for (int t = 0; t < 128; ++t) {
    const int s = d ? (127 - t) : t;
    f32x4 acc[8];
#pragma unroll
    for (int nt = 0; nt < 8; ++nt) acc[nt] = (f32x4){0.f, 0.f, 0.f, 0.f};

    // kt0..3: register-stationary
#pragma unroll
    for (int kt = 0; kt < 4; ++kt) {
      short8 a = *(const short8*)&hlds[p][l15 * 264 + kt * 32 + quad * 8];
#pragma unroll
      for (int nt = 0; nt < 8; ++nt) acc[nt] = mfma16(a, bs[kt][nt], acc[nt]);
    }
    // kt4..5: LDS cache
#pragma unroll
    for (int kt2 = 0; kt2 < 2; ++kt2) {
      short8 a = *(const short8*)&hlds[p][l15 * 264 + (4 + kt2) * 32 + quad * 8];
#pragma unroll
      for (int nt = 0; nt < 8; ++nt) {
        short8 bfr = *(const short8*)&wlds[(size_t)(((wave * 8 + nt) * 2 + kt2) * 64 + lane) * 8];
        acc[nt] = mfma16(a, bfr, acc[nt]);
      }
    }
    // kt6..7: streamed from L2 (same addresses every step -> L2-resident)
#pragma unroll
    for (int kt = 6; kt < 8; ++kt) {
      short8 a = *(const short8*)&hlds[p][l15 * 264 + kt * 32 + quad * 8];
#pragma unroll
      for (int nt = 0; nt < 8; ++nt) {
        short8 bfr = *(const short8*)(Wrow[nt] + kt * 32);
        acc[nt] = mfma16(a, bfr, acc[nt]);
      }
    }

    // ---- register-only cell epilogue: 8 cells per lane ----
#pragma unroll
    for (int h2 = 0; h2 < 2; ++h2) {
      const int u = 32 * wave + 16 * h2 + l15;
#pragma unroll
      for (int r = 0; r < 4; ++r) {
        const int b = quad * 4 + r, gb = b0 + b, ci = h2 * 4 + r;
        const float4 xv = xg[ci];
        float gi = clampf(acc[0 + h2][r], 64.f) + xv.x;
        float gf = clampf(acc[2 + h2][r], 64.f) + xv.y;
        float gg = clampf(acc[4 + h2][r], 64.f) + xv.z;
        float go = clampf(acc[6 + h2][r], 64.f) + xv.w;
        float c = clampf(sigf(gf) * creg[ci] + sigf(gi) * tanh_f(gg), 256.f);
        creg[ci] = c;
        float h = clampf(sigf(go) * tanh_f(c), 4.f);
        out[((size_t)gb * 128 + s) * 512 + (size_t)d * 256 + u] = __float2bfloat16(h);
        if (layer == 1 && d == 0 && t == 127)
          g_HID[gb * 256 + u] = h;                     // decoder hidden0, exact f32
        hlds[p ^ 1][b * 264 + u] = __float2bfloat16(h);
      }
    }

    // prefetch X for step t+1 (hides under next step's MFMA phase)
    if (t < 127) {
      const int sn = d ? (126 - t) : (t + 1);
#pragma unroll
      for (int h2 = 0; h2 < 2; ++h2) {
        const int u = 32 * wave + 16 * h2 + l15;
#pragma unroll
        for (int r = 0; r < 4; ++r) {
          const int gb = b0 + quad * 4 + r;
          xg[h2 * 4 + r] = *(const float4*)&X[(((size_t)gb * 128 + sn) * 256 + u) * 4];
        }
      }
    }
    __syncthreads();
    p ^= 1;
  }
}

// ---------------------------------------------------------------------------
// Per decoder step: token select (+argmax of prev pred), hWa, energies,
// softmax, context; writes g_XIN=[emb|ctx] and g_HC[256:768]=ctx. grid=64 (b).
__global__ __launch_bounds__(256) void attn_step(int step,
                                                 const int* __restrict__ trg,
                                                 const unsigned char* __restrict__ tfm,
                                                 const float* __restrict__ dec_emb,
                                                 const float* __restrict__ Wa,  // [256][768] f32
                                                 const float* __restrict__ ba,
                                                 const float* __restrict__ vv,
                                                 const float* __restrict__ outp) // d_out f32
{
  int b = blockIdx.x, tid = threadIdx.x;
  __shared__ float sh[256], hb[256], vsh[256], es[128], red[256];
  __shared__ int ridx[256];
  __shared__ int stok;

  if (step == 1) {
    if (tid == 0) stok = trg[b * 64];
  } else {
    const float* pr = outp + (size_t)b * 640000 + (size_t)(step - 1) * 10000;
    float bv = -3.4e38f; int bi = 0;
    for (int v2 = tid; v2 < 10000; v2 += 256) {
      float pv = pr[v2];
      if (pv > bv) { bv = pv; bi = v2; }   // ascending scan: first-max kept
    }
    red[tid] = bv; ridx[tid] = bi;
    __syncthreads();
    for (int off = 128; off; off >>= 1) {
      if (tid < off) {
        float ov = red[tid + off]; int oi = ridx[tid + off];
        if (ov > red[tid] || (ov == red[tid] && oi < ridx[tid])) { red[tid] = ov; ridx[tid] = oi; }
      }
      __syncthreads();
    }
    if (tid == 0) {
      int k = step - 1;
      // true under both uint8-bool and int32-bool storage (mask is all-True)
      int tf = (int)tfm[k] | (int)tfm[4 * k];
      int tok = tf ? trg[b * 64 + k] : ridx[0];
      if (tok < 0 || tok >= 10000) tok = 0;            // defensive
      stok = tok;
    }
    __syncthreads();
  }

  sh[tid]  = g_HID[b * 256 + tid];
  vsh[tid] = vv[tid];
  __syncthreads();

  // hWa[j] + ba[j]  (first 256 cols of Wa act on hidden) — f32 weights
  {
    float acc = 0.f;
    const float* wr = Wa + (size_t)tid * 768;
    for (int k4 = 0; k4 < 256; k4 += 4) {
      float4 w4 = *(const float4*)(wr + k4);
      acc += sh[k4] * w4.x + sh[k4 + 1] * w4.y + sh[k4 + 2] * w4.z + sh[k4 + 3] * w4.w;
    }
    hb[tid] = clampf(acc + ba[tid], 64.f);
  }
  __syncthreads();

  // energies: wave w handles s = w, w+4, ...
  int wv = tid >> 6, ln = tid & 63;
  for (int s = wv; s < 128; s += 4) {
    const float* Er = g_EWA + ((size_t)b * 128 + s) * 256;
    float part = 0.f;
#pragma unroll
    for (int jj = 0; jj < 4; ++jj) {
      int j = ln + 64 * jj;
      part += tanh_f(hb[j] + Er[j]) * vsh[j];
    }
    part += __shfl_down(part, 32);
    part += __shfl_down(part, 16);
    part += __shfl_down(part, 8);
    part += __shfl_down(part, 4);
    part += __shfl_down(part, 2);
    part += __shfl_down(part, 1);
    if (ln == 0) es[s] = clampf(part, 512.f);
  }
  __syncthreads();

  // softmax over s
  red[tid] = (tid < 128) ? es[tid] : -3.4e38f;
  __syncthreads();
  for (int off = 128; off; off >>= 1) { if (tid < off) red[tid] = fmaxf(red[tid], red[tid + off]); __syncthreads(); }
  float mx = red[0];
  __syncthreads();
  float pexp = (tid < 128) ? fexp2((es[tid] - mx) * 1.44269504f) : 0.f;
  red[tid] = pexp;
  __syncthreads();
  for (int off = 128; off; off >>= 1) { if (tid < off) red[tid] += red[tid + off]; __syncthreads(); }
  float inv = frcp(red[0]);
  __syncthreads();
  if (tid < 128) es[tid] = pexp * inv;
  __syncthreads();

  // context
  float c0 = 0.f, c1 = 0.f;
  for (int s = 0; s < 128; ++s) {
    const bf16* er = g_ENC + ((size_t)b * 128 + s) * 512;
    float a = es[s];
    c0 += a * b2f(er[tid]);
    c1 += a * b2f(er[tid + 256]);
  }
  c0 = clampf(c0, 16.f);
  c1 = clampf(c1, 16.f);
  g_XIN[(size_t)b * 640 + 128 + tid] = __float2bfloat16(c0);
  g_XIN[(size_t)b * 640 + 384 + tid] = __float2bfloat16(c1);
  g_HC [(size_t)b * 768 + 256 + tid] = __float2bfloat16(c0);
  g_HC [(size_t)b * 768 + 512 + tid] = __float2bfloat16(c1);
  if (tid < 128)
    g_XIN[(size_t)b * 640 + tid] = __float2bfloat16(dec_emb[(size_t)stok * 128 + tid]);
}

// ---------------------------------------------------------------------------
// g = xin @ dWih.T + db fused with cell: c=sig(i)*tanh(g); h=sig(o)*tanh(c)
// grid = 16: block bx owns u-slice [16bx,16bx+16); wave = gate.
__global__ __launch_bounds__(256) void dec_gemm_cell(const float* __restrict__ db) {
  __shared__ float gst[64 * 68];
  const int tid = threadIdx.x;
  const int wave = tid >> 6, lane = tid & 63, l15 = lane & 15, quad = lane >> 4;
  const int u0 = blockIdx.x * 16;

  f32x4 acc[4];
#pragma unroll
  for (int mt = 0; mt < 4; ++mt) acc[mt] = (f32x4){0.f, 0.f, 0.f, 0.f};

  const bf16* Brow = g_WBF + OFF_DWIH + (size_t)(wave * 256 + u0 + l15) * 640 + quad * 8;
  for (int kt = 0; kt < 20; ++kt) {
    short8 bfr = *(const short8*)(Brow + kt * 32);
#pragma unroll
    for (int mt = 0; mt < 4; ++mt) {
      short8 a = *(const short8*)(g_XIN + (size_t)(16 * mt + l15) * 640 + kt * 32 + quad * 8);
      acc[mt] = mfma16(a, bfr, acc[mt]);
    }
  }
#pragma unroll
  for (int mt = 0; mt < 4; ++mt)
#pragma unroll
    for (int r = 0; r < 4; ++r)
      gst[(16 * mt + quad * 4 + r) * 68 + wave * 16 + l15] = clampf(acc[mt][r], 64.f);
  __syncthreads();

  for (int p = tid; p < 1024; p += 256) {
    int b = p >> 4, uu = p & 15;
    int u = u0 + uu;
    float gi = gst[b * 68 + 0  + uu] + db[u];
    float gg = gst[b * 68 + 32 + uu] + db[512 + u];
    float go = gst[b * 68 + 48 + uu] + db[768 + u];
    float c = sigf(gi) * tanh_f(gg);
    float h = clampf(sigf(go) * tanh_f(c), 4.f);
    g_HID[b * 256 + u] = h;
    g_HC[(size_t)b * 768 + u] = __float2bfloat16(h);
  }
}

// ---------------------------------------------------------------------------
__global__ __launch_bounds__(256) void zero_t0(float* __restrict__ outp) {
  int idx = blockIdx.x * 256 + threadIdx.x;        // 64*10000
  int b = idx / 10000, v = idx - b * 10000;
  outp[(size_t)b * 640000 + v] = 0.f;
}

// ---------------------------------------------------------------------------
extern "C" void kernel_launch(void* const* d_in, const int* in_sizes, int n_in,
                              void* d_out, int out_size, void* d_ws, size_t ws_size,
                              hipStream_t stream) {
  (void)in_sizes; (void)n_in; (void)out_size; (void)d_ws; (void)ws_size;

  const int*   src     = (const int*)   d_in[0];
  const int*   trg     = (const int*)   d_in[1];
  const unsigned char* tfm = (const unsigned char*) d_in[2];
  const float* enc_emb = (const float*) d_in[3];
  const float* e1f_Wih = (const float*) d_in[4];
  const float* e1f_Whh = (const float*) d_in[5];
  const float* e1f_b   = (const float*) d_in[6];
  const float* e1b_Wih = (const float*) d_in[7];
  const float* e1b_Whh = (const float*) d_in[8];
  const float* e1b_b   = (const float*) d_in[9];
  const float* e2f_Wih = (const float*) d_in[10];
  const float* e2f_Whh = (const float*) d_in[11];
  const float* e2f_b   = (const float*) d_in[12];
  const float* e2b_Wih = (const float*) d_in[13];
  const float* e2b_Whh = (const float*) d_in[14];
  const float* e2b_b   = (const float*) d_in[15];
  const float* dec_emb = (const float*) d_in[16];
  const float* Wa      = (const float*) d_in[17];
  const float* ba      = (const float*) d_in[18];
  const float* vv      = (const float*) d_in[19];
  const float* dWih    = (const float*) d_in[20];
  const float* db      = (const float*) d_in[21];
  const float* Wfc     = (const float*) d_in[22];
  const float* bfc     = (const float*) d_in[23];
  float* outp = (float*) d_out;

  // ---- weight conversion f32 -> bf16 pool ----
  cvt_w<<<128,  256, 0, stream>>>(e1f_Wih, OFF_E1F_WIH, 131072);
  cvt_w<<<128,  256, 0, stream>>>(e1b_Wih, OFF_E1B_WIH, 131072);
  cvt_w<<<512,  256, 0, stream>>>(e2f_Wih, OFF_E2F_WIH, 524288);
  cvt_w<<<512,  256, 0, stream>>>(e2b_Wih, OFF_E2B_WIH, 524288);
  cvt_w<<<256,  256, 0, stream>>>(e1f_Whh, OFF_E1F_WHH, 262144);
  cvt_w<<<256,  256, 0, stream>>>(e1b_Whh, OFF_E1B_WHH, 262144);
  cvt_w<<<256,  256, 0, stream>>>(e2f_Whh, OFF_E2F_WHH, 262144);
  cvt_w<<<256,  256, 0, stream>>>(e2b_Whh, OFF_E2B_WHH, 262144);
  cvt_w<<<640,  256, 0, stream>>>(dWih,    OFF_DWIH,    655360);
  cvt_w<<<7500, 256, 0, stream>>>(Wfc,     OFF_WFC,     7680000);
  cvt_w<<<192,  256, 0, stream>>>(Wa,      OFF_WA,      196608);

  // ---- encoder ----
  embed_k<<<1024, 256, 0, stream>>>(src, enc_emb);
  gemm_x1<<<dim3(128, 16), 256, 0, stream>>>(OFF_E1F_WIH, e1f_b, 0);
  gemm_x1<<<dim3(128, 16), 256, 0, stream>>>(OFF_E1B_WIH, e1b_b, 1);
  lstm_batch<<<8, 512, 0, stream>>>(OFF_E1F_WHH, OFF_E1B_WHH, 0);
  gemm_x2<<<dim3(128, 16), 256, 0, stream>>>(OFF_E2F_WIH, e2f_b, 0);
  gemm_x2<<<dim3(128, 16), 256, 0, stream>>>(OFF_E2B_WIH, e2b_b, 1);
  lstm_batch<<<8, 512, 0, stream>>>(OFF_E2F_WHH, OFF_E2B_WHH, 1);
  gemm_ewa<<<dim3(128, 4), 256, 0, stream>>>();
  zero_t0<<<2500, 256, 0, stream>>>(outp);

  // ---- decoder ----
  for (int i = 1; i < 64; ++i) {
    attn_step<<<64, 256, 0, stream>>>(i, trg, tfm, dec_emb, Wa, ba, vv, outp);
    dec_gemm_cell<<<16, 256, 0, stream>>>(db);
    gemm_pred<<<dim3(1, 157), 256, 0, stream>>>(bfc, outp, i);
  }
}